// Round 4
// baseline (373.694 us; speedup 1.0000x reference)
//
#include <hip/hip_runtime.h>
#include <stdint.h>

typedef __bf16 bf16;
typedef __bf16 bf16x4 __attribute__((ext_vector_type(4)));
typedef __bf16 bf16x8 __attribute__((ext_vector_type(8)));
typedef float  f32x4  __attribute__((ext_vector_type(4)));

#define MFMA16(a,b,c) __builtin_amdgcn_mfma_f32_16x16x32_bf16((a),(b),(c),0,0,0)

// LDS layout (single array, 32672 B, 4 blocks/CU):
//   [QB..) q 49 rows x ST   (later O, same layout)        5096 elems
//   [KB..) k 49 rows x ST                                 5096 elems
//   [VB..) v^T 96 x 64, k-permuted + XOR-swizzled slots   6144 elems
// Reads may run past a region's stored rows (rows 49..63): they land in the
// next region's data, which is fully written BEFORE the single barrier and
// never overwritten after it (O writes are masked to rows <= 48). All such
// garbage outputs are masked or discarded.
#define ST 104        // row stride elems = 208 B (16B-aligned for b128)
#define QB 0
#define KB 5096
#define VB 10192
#define LDS_ELEMS 16336

// weight prep: fp32 [K][N] -> bf16 [N][K] (transposed) in workspace
__global__ void prep_weights(const float* __restrict__ qkv_w,
                             const float* __restrict__ proj_w,
                             bf16* __restrict__ wT) {
    int i = blockIdx.x * 256 + threadIdx.x;
    if (i < 288 * 96) {
        int j = i / 96, c = i - j * 96;
        wT[i] = (bf16)qkv_w[c * 288 + j];
    } else if (i < 288 * 96 + 96 * 96) {
        int t = i - 288 * 96;
        int j = t / 96, c = t - j * 96;
        wT[i] = (bf16)proj_w[c * 96 + j];
    }
}

__global__ __launch_bounds__(256, 4)
void win_attn_kernel(const float* __restrict__ x,
                     const float* __restrict__ qkv_b,
                     const float* __restrict__ proj_b,
                     const bf16* __restrict__ qkvwT,   // [288][96] bf16
                     const bf16* __restrict__ projwT,  // [96][96] bf16
                     float* __restrict__ out)
{
    __shared__ bf16 lds[LDS_ELEMS];

    const int tid  = threadIdx.x;
    const int wid  = tid >> 6;
    const int lane = tid & 63;
    const int lm   = lane & 15;   // row/col within 16-tile
    const int lq   = lane >> 4;   // quad 0..3

    const int wi = blockIdx.x;
    const int b  = wi >> 10;          // 1024 windows per batch image
    const int wr = wi & 1023;
    const int h0 = (wr >> 5) * 7;
    const int w0 = (wr & 31) * 7;

    // ---------------- Phase 1a: x A-fragments DIRECT from global (no staging) -----
    // Lane (lm,lq), tile tt: token = tt*16+lm, feats ks*32+lq*8 .. +8 -> two
    // dwordx4 loads per fragment (contiguous per token, 16B aligned).
    // Window = 18.8 KB fp32 -> L1-resident; 4x per-wave redundancy is cheap.
    // tt=3: only token 48 (lm==0) is real; others zeroed in registers.
    bf16x8 afr[4][3];
    {
        const float* xbase = x + ((size_t)(b * 224 + h0) * 224 + w0) * 96;
        #pragma unroll
        for (int tt = 0; tt < 4; ++tt) {
            const int token0 = tt * 16 + lm;
            const int token  = (token0 < 49) ? token0 : 48;   // clamp: loads stay in-bounds
            const int pr = token / 7, pc = token - pr * 7;
            const float* tp = xbase + ((size_t)pr * 224 + pc) * 96;
            #pragma unroll
            for (int ks = 0; ks < 3; ++ks) {
                const float* p = tp + ks * 32 + lq * 8;
                const float4 v0 = *(const float4*)p;
                const float4 v1 = *(const float4*)(p + 4);
                bf16x8 bv = { (bf16)v0.x, (bf16)v0.y, (bf16)v0.z, (bf16)v0.w,
                              (bf16)v1.x, (bf16)v1.y, (bf16)v1.z, (bf16)v1.w };
                afr[tt][ks] = (token0 < 49) ? bv : (bf16x8){};
            }
        }
    }

    // ---------------- Phase 1b: QKV GEMM ----------------
    // q,k: swapped mfma(W^T, x) -> feat-major C -> packed b64 token-major stores,
    //      rows masked to <=48. Softmax scale (1/sqrt(32))*log2e folded into q.
    // v:   original orientation -> v^T stored in PV's PERMUTED slot order
    //      (slot = 32*(mt>>1) + 8*lq + 4*(mt&1) + i), XOR-swizzled per row.
    {
        const float Cs = 0.2550348607051632f;   // (1/sqrt(32)) * log2(e)
        #pragma unroll
        for (int i = 0; i < 5; ++i) {
            const int ft = wid + i * 4;
            if (i < 4 || wid < 2) {             // ft < 18, wave-uniform
                bf16x8 wf[3];
                #pragma unroll
                for (int ks = 0; ks < 3; ++ks)
                    wf[ks] = *(const bf16x8*)&qkvwT[(size_t)(ft * 16 + lm) * 96 + ks * 32 + lq * 8];
                if (ft < 12) {          // q (ft<6) or k (6<=ft<12), wave-uniform branch
                    const f32x4 bias4 = *(const f32x4*)(qkv_b + ft * 16 + lq * 4);
                    f32x4 acc[4];
                    #pragma unroll
                    for (int tt = 0; tt < 4; ++tt) acc[tt] = bias4;
                    #pragma unroll
                    for (int ks = 0; ks < 3; ++ks)
                        #pragma unroll
                        for (int tt = 0; tt < 4; ++tt)
                            acc[tt] = MFMA16(wf[ks], afr[tt][ks], acc[tt]);
                    const bool isq = (ft < 6);
                    const int base = isq ? QB : KB;
                    const int col  = (isq ? ft : ft - 6) * 16 + lq * 4;
                    #pragma unroll
                    for (int tt = 0; tt < 4; ++tt) {
                        if (tt < 3 || lm == 0) {
                            f32x4 a = acc[tt];
                            if (isq) a *= Cs;
                            bf16x4 pv = { (bf16)a[0], (bf16)a[1], (bf16)a[2], (bf16)a[3] };
                            *(bf16x4*)&lds[base + (tt * 16 + lm) * ST + col] = pv;
                        }
                    }
                } else {                // v -> v^T[d][permuted slot], XOR-swizzled
                    const int d0 = (ft - 12) * 16 + lm;
                    const float bias = qkv_b[192 + d0];
                    f32x4 acc[4];
                    #pragma unroll
                    for (int mt = 0; mt < 4; ++mt) acc[mt] = (f32x4){bias, bias, bias, bias};
                    #pragma unroll
                    for (int ks = 0; ks < 3; ++ks)
                        #pragma unroll
                        for (int mt = 0; mt < 4; ++mt)
                            acc[mt] = MFMA16(afr[mt][ks], wf[ks], acc[mt]);
                    #pragma unroll
                    for (int mt = 0; mt < 4; ++mt) {
                        bf16x4 pv = { (bf16)acc[mt][0], (bf16)acc[mt][1],
                                      (bf16)acc[mt][2], (bf16)acc[mt][3] };
                        const int g = (mt >> 1) * 4 + lq;          // permuted group-of-8
                        *(bf16x4*)&lds[VB + d0 * 64 + ((g ^ (d0 & 7)) << 3) + ((mt & 1) << 2)] = pv;
                    }
                }
            }
        }
    }
    __syncthreads();   // the ONLY barrier: q, k, v^T ready for cross-wave reads

    // ---------------- Phase 2: attention, qt-split across ALL 4 waves ----------------
    // Wave w owns qtok tile w (rows w*16+lm) for all 3 heads. S^T = mfma(k,q) puts
    // ktok on the register axis -> exp2 packs DIRECTLY into the PV B-fragment
    // (v^T pre-permuted to match). Row sum = scalar + 2 shuffles; norm deferred to O.
    // O overwrites this wave's OWN q rows only -> no barrier needed afterwards.
    {
        const int qrow = wid * 16 + lm;
        const f32x4 zf = {0.f, 0.f, 0.f, 0.f};
        #pragma unroll
        for (int h = 0; h < 3; ++h) {
            const bf16x8 aqv = *(const bf16x8*)&lds[QB + qrow * ST + h * 32 + lq * 8];
            bf16x8 bkv[4];
            #pragma unroll
            for (int kt = 0; kt < 4; ++kt)
                bkv[kt] = *(const bf16x8*)&lds[KB + (kt * 16 + lm) * ST + h * 32 + lq * 8];
            f32x4 s0 = MFMA16(bkv[0], aqv, zf);
            f32x4 s1 = MFMA16(bkv[1], aqv, zf);
            f32x4 s2 = MFMA16(bkv[2], aqv, zf);
            f32x4 s3 = MFMA16(bkv[3], aqv, zf);
            // lane holds ktok = 16*kt + 4*lq + i; tiles 0..2 all valid (ktok<48),
            // tile 3: only ktok=48 (lq==0,i==0) real.
            float p0  = exp2f(s0[0]), p1  = exp2f(s0[1]), p2  = exp2f(s0[2]), p3  = exp2f(s0[3]);
            float p4  = exp2f(s1[0]), p5  = exp2f(s1[1]), p6  = exp2f(s1[2]), p7  = exp2f(s1[3]);
            float p8  = exp2f(s2[0]), p9  = exp2f(s2[1]), p10 = exp2f(s2[2]), p11 = exp2f(s2[3]);
            float p48 = (lq == 0) ? exp2f(s3[0]) : 0.f;
            float part = ((p0 + p1) + (p2 + p3)) + ((p4 + p5) + (p6 + p7))
                       + ((p8 + p9) + (p10 + p11)) + p48;
            part += __shfl_xor(part, 16);
            part += __shfl_xor(part, 32);
            const float rin = __builtin_amdgcn_rcpf(part);
            bf16x8 ap0 = { (bf16)p0, (bf16)p1, (bf16)p2,  (bf16)p3,
                           (bf16)p4, (bf16)p5, (bf16)p6,  (bf16)p7 };
            bf16x8 ap1 = { (bf16)p8, (bf16)p9, (bf16)p10, (bf16)p11,
                           (bf16)p48, (bf16)0.f, (bf16)0.f, (bf16)0.f };
            bf16x8 av00, av01, av10, av11;
            {
                const int fr0 = h * 32 + lm, fr1 = h * 32 + 16 + lm;
                av00 = *(const bf16x8*)&lds[VB + fr0 * 64 + (((0 + lq) ^ (fr0 & 7)) << 3)];
                av01 = *(const bf16x8*)&lds[VB + fr1 * 64 + (((0 + lq) ^ (fr1 & 7)) << 3)];
                av10 = *(const bf16x8*)&lds[VB + fr0 * 64 + (((4 + lq) ^ (fr0 & 7)) << 3)];
                av11 = *(const bf16x8*)&lds[VB + fr1 * 64 + (((4 + lq) ^ (fr1 & 7)) << 3)];
            }
            f32x4 o0 = MFMA16(av00, ap0, zf);
            o0 = MFMA16(av10, ap1, o0);
            f32x4 o1 = MFMA16(av01, ap0, zf);
            o1 = MFMA16(av11, ap1, o1);
            o0 *= rin;
            o1 *= rin;
            if (wid < 3 || lm == 0) {
                bf16x4 w0v = { (bf16)o0[0], (bf16)o0[1], (bf16)o0[2], (bf16)o0[3] };
                bf16x4 w1v = { (bf16)o1[0], (bf16)o1[1], (bf16)o1[2], (bf16)o1[3] };
                *(bf16x4*)&lds[QB + qrow * ST + h * 32 + lq * 4]      = w0v;
                *(bf16x4*)&lds[QB + qrow * ST + h * 32 + 16 + lq * 4] = w1v;
            }
        }
    }
    // NO __syncthreads here: proj wave tt reads exactly the O rows (tt*16+lm) that
    // THIS wave wrote above; DS ops are processed in wave order, so the read
    // observes the write. The fence only stops compiler reordering.
    asm volatile("" ::: "memory");

    // ---------------- Phase 3: proj swapped: mfma(W^T, O); float4 stores ----------------
    {
        const int tt = wid;
        bf16x8 of[3];
        #pragma unroll
        for (int ks = 0; ks < 3; ++ks)
            of[ks] = *(const bf16x8*)&lds[QB + (tt * 16 + lm) * ST + ks * 32 + lq * 8];
        const int token = tt * 16 + lm;
        const int tv = (token < 49) ? token : 0;
        const int pr = tv / 7, pc = tv - pr * 7;
        float* obase = out + ((size_t)(b * 224 + h0 + pr) * 224 + (w0 + pc)) * 96 + lq * 4;
        #pragma unroll
        for (int ft = 0; ft < 6; ++ft) {
            bf16x8 wp[3];
            #pragma unroll
            for (int ks = 0; ks < 3; ++ks)
                wp[ks] = *(const bf16x8*)&projwT[(size_t)(ft * 16 + lm) * 96 + ks * 32 + lq * 8];
            f32x4 acc = *(const f32x4*)(proj_b + ft * 16 + lq * 4);
            #pragma unroll
            for (int ks = 0; ks < 3; ++ks)
                acc = MFMA16(wp[ks], of[ks], acc);
            if (token < 49)
                *(f32x4*)(obase + ft * 16) = acc;
        }
    }
}

extern "C" void kernel_launch(void* const* d_in, const int* in_sizes, int n_in,
                              void* d_out, int out_size, void* d_ws, size_t ws_size,
                              hipStream_t stream) {
    const float* x      = (const float*)d_in[0];
    const float* qkv_w  = (const float*)d_in[1];
    const float* qkv_b  = (const float*)d_in[2];
    const float* proj_w = (const float*)d_in[3];
    const float* proj_b = (const float*)d_in[4];
    float* out = (float*)d_out;

    bf16* wT = (bf16*)d_ws;                 // 288*96 + 96*96 bf16 = 73728 B
    const int n_w = 288 * 96 + 96 * 96;
    prep_weights<<<(n_w + 255) / 256, 256, 0, stream>>>(qkv_w, proj_w, wT);
    win_attn_kernel<<<8192, 256, 0, stream>>>(x, qkv_b, proj_b,
                                              wT, wT + 288 * 96, out);
}

// Round 5
// 331.957 us; speedup vs baseline: 1.1257x; 1.1257x over previous
//
#include <hip/hip_runtime.h>
#include <stdint.h>

typedef __bf16 bf16;
typedef __bf16 bf16x4 __attribute__((ext_vector_type(4)));
typedef __bf16 bf16x8 __attribute__((ext_vector_type(8)));
typedef float  f32x4  __attribute__((ext_vector_type(4)));

#define MFMA16(a,b,c) __builtin_amdgcn_mfma_f32_16x16x32_bf16((a),(b),(c),0,0,0)

// LDS layout (single array, 32672 B, 4 blocks/CU):
//   [QB..) q 49 rows x ST   (later O, same layout)        5096 elems
//   [KB..) k 49 rows x ST                                 5096 elems
//   [VB..) x staging [49][ST], then v^T 96 x 64 (k-permuted + XOR-swizzled)
// Reads may run past a region's stored rows (rows 49..63): they land in the
// next region's data, which is fully written before the last barrier and never
// overwritten after it (O writes masked to rows <= 48). Garbage outputs are
// masked or discarded.
#define ST 104        // row stride elems = 208 B (16B-aligned for b128)
#define QB 0
#define KB 5096
#define VB 10192
#define LDS_ELEMS 16336

// weight prep: fp32 [K][N] -> bf16 [N][K] (transposed) in workspace
__global__ void prep_weights(const float* __restrict__ qkv_w,
                             const float* __restrict__ proj_w,
                             bf16* __restrict__ wT) {
    int i = blockIdx.x * 256 + threadIdx.x;
    if (i < 288 * 96) {
        int j = i / 96, c = i - j * 96;
        wT[i] = (bf16)qkv_w[c * 288 + j];
    } else if (i < 288 * 96 + 96 * 96) {
        int t = i - 288 * 96;
        int j = t / 96, c = t - j * 96;
        wT[i] = (bf16)proj_w[c * 96 + j];
    }
}

__global__ __launch_bounds__(256, 4)
void win_attn_kernel(const float* __restrict__ x,
                     const float* __restrict__ qkv_b,
                     const float* __restrict__ proj_b,
                     const bf16* __restrict__ qkvwT,   // [288][96] bf16
                     const bf16* __restrict__ projwT,  // [96][96] bf16
                     float* __restrict__ out)
{
    __shared__ bf16 lds[LDS_ELEMS];

    const int tid  = threadIdx.x;
    const int wid  = tid >> 6;
    const int lane = tid & 63;
    const int lm   = lane & 15;   // row/col within 16-tile
    const int lq   = lane >> 4;   // quad 0..3

    const int wi = blockIdx.x;
    const int b  = wi >> 10;          // 1024 windows per batch image
    const int wr = wi & 1023;
    const int h0 = (wr >> 5) * 7;
    const int w0 = (wr & 31) * 7;

    // ---------------- Phase 0: stage x window (49 real rows), coalesced ----------------
    {
        const float* xbase = x + ((size_t)(b * 224 + h0) * 224 + w0) * 96;
        for (int t = tid; t < 49 * 12; t += 256) {
            const int pix = t / 12, f8 = t - pix * 12;
            const int pr = pix / 7, pc = pix - pr * 7;
            const float* p = xbase + ((size_t)pr * 224 + pc) * 96 + f8 * 8;
            const float4 v0 = *(const float4*)p;
            const float4 v1 = *(const float4*)(p + 4);
            bf16x8 bv = { (bf16)v0.x, (bf16)v0.y, (bf16)v0.z, (bf16)v0.w,
                          (bf16)v1.x, (bf16)v1.y, (bf16)v1.z, (bf16)v1.w };
            *(bf16x8*)&lds[VB + pix * ST + f8 * 8] = bv;
        }
    }
    __syncthreads();   // b1: x staged

    // ---------------- Phase 1a: x fragments -> registers (lane lm = token) -------
    // tt=3 covers tokens 48..63: only token 48 (lm==0) real; others zeroed.
    bf16x8 afr[4][3];
    #pragma unroll
    for (int tt = 0; tt < 4; ++tt)
        #pragma unroll
        for (int ks = 0; ks < 3; ++ks) {
            if (tt < 3 || lm == 0)
                afr[tt][ks] = *(const bf16x8*)&lds[VB + (tt * 16 + lm) * ST + ks * 32 + lq * 8];
            else
                afr[tt][ks] = (bf16x8){};
        }
    __syncthreads();   // b2: x region free -> v^T may be written

    // ---------------- Phase 1b: QKV GEMM ----------------
    // q,k: swapped mfma(W^T, x) -> feat-major C -> packed b64 token-major stores,
    //      rows masked to <=48. Softmax scale (1/sqrt(32))*log2e folded into q.
    // v:   original orientation -> v^T stored in PV's PERMUTED slot order
    //      (slot = 32*(mt>>1) + 8*lq + 4*(mt&1) + i), XOR-swizzled per row.
    {
        const float Cs = 0.2550348607051632f;   // (1/sqrt(32)) * log2(e)
        for (int ft = wid; ft < 18; ft += 4) {
            bf16x8 wf[3];
            #pragma unroll
            for (int ks = 0; ks < 3; ++ks)
                wf[ks] = *(const bf16x8*)&qkvwT[(size_t)(ft * 16 + lm) * 96 + ks * 32 + lq * 8];
            if (ft < 12) {          // q (ft<6) or k (6<=ft<12), wave-uniform branch
                const f32x4 bias4 = *(const f32x4*)(qkv_b + ft * 16 + lq * 4);
                f32x4 acc[4];
                #pragma unroll
                for (int tt = 0; tt < 4; ++tt) acc[tt] = bias4;
                #pragma unroll
                for (int ks = 0; ks < 3; ++ks)
                    #pragma unroll
                    for (int tt = 0; tt < 4; ++tt)
                        acc[tt] = MFMA16(wf[ks], afr[tt][ks], acc[tt]);
                const bool isq = (ft < 6);
                const int base = isq ? QB : KB;
                const int col  = (isq ? ft : ft - 6) * 16 + lq * 4;
                #pragma unroll
                for (int tt = 0; tt < 4; ++tt) {
                    if (tt < 3 || lm == 0) {
                        f32x4 a = acc[tt];
                        if (isq) a *= Cs;
                        bf16x4 pv = { (bf16)a[0], (bf16)a[1], (bf16)a[2], (bf16)a[3] };
                        *(bf16x4*)&lds[base + (tt * 16 + lm) * ST + col] = pv;
                    }
                }
            } else {                // v -> v^T[d][permuted slot], XOR-swizzled
                const int d0 = (ft - 12) * 16 + lm;
                const float bias = qkv_b[192 + d0];
                f32x4 acc[4];
                #pragma unroll
                for (int mt = 0; mt < 4; ++mt) acc[mt] = (f32x4){bias, bias, bias, bias};
                #pragma unroll
                for (int ks = 0; ks < 3; ++ks)
                    #pragma unroll
                    for (int mt = 0; mt < 4; ++mt)
                        acc[mt] = MFMA16(afr[mt][ks], wf[ks], acc[mt]);
                #pragma unroll
                for (int mt = 0; mt < 4; ++mt) {
                    bf16x4 pv = { (bf16)acc[mt][0], (bf16)acc[mt][1],
                                  (bf16)acc[mt][2], (bf16)acc[mt][3] };
                    const int g = (mt >> 1) * 4 + lq;          // permuted group-of-8
                    *(bf16x4*)&lds[VB + d0 * 64 + ((g ^ (d0 & 7)) << 3) + ((mt & 1) << 2)] = pv;
                }
            }
        }
    }
    __syncthreads();   // b3: q, k, v^T ready for cross-wave reads

    // ---------------- Phase 2: attention, qt-split across ALL 4 waves ----------------
    // Wave w owns qtok tile w (rows w*16+lm) for all 3 heads. S^T = mfma(k,q) puts
    // ktok on the register axis -> exp2 packs DIRECTLY into the PV B-fragment
    // (v^T pre-permuted to match). Row sum = scalar + 2 shuffles; norm deferred to O.
    // O overwrites this wave's OWN q rows only -> no barrier needed afterwards.
    {
        const int qrow = wid * 16 + lm;
        const f32x4 zf = {0.f, 0.f, 0.f, 0.f};
        #pragma unroll
        for (int h = 0; h < 3; ++h) {
            const bf16x8 aqv = *(const bf16x8*)&lds[QB + qrow * ST + h * 32 + lq * 8];
            bf16x8 bkv[4];
            #pragma unroll
            for (int kt = 0; kt < 4; ++kt)
                bkv[kt] = *(const bf16x8*)&lds[KB + (kt * 16 + lm) * ST + h * 32 + lq * 8];
            f32x4 s0 = MFMA16(bkv[0], aqv, zf);
            f32x4 s1 = MFMA16(bkv[1], aqv, zf);
            f32x4 s2 = MFMA16(bkv[2], aqv, zf);
            f32x4 s3 = MFMA16(bkv[3], aqv, zf);
            // lane holds ktok = 16*kt + 4*lq + i; tiles 0..2 all valid (ktok<48),
            // tile 3: only ktok=48 (lq==0,i==0) real.
            float p0  = exp2f(s0[0]), p1  = exp2f(s0[1]), p2  = exp2f(s0[2]), p3  = exp2f(s0[3]);
            float p4  = exp2f(s1[0]), p5  = exp2f(s1[1]), p6  = exp2f(s1[2]), p7  = exp2f(s1[3]);
            float p8  = exp2f(s2[0]), p9  = exp2f(s2[1]), p10 = exp2f(s2[2]), p11 = exp2f(s2[3]);
            float p48 = (lq == 0) ? exp2f(s3[0]) : 0.f;
            float part = ((p0 + p1) + (p2 + p3)) + ((p4 + p5) + (p6 + p7))
                       + ((p8 + p9) + (p10 + p11)) + p48;
            part += __shfl_xor(part, 16);
            part += __shfl_xor(part, 32);
            const float rin = __builtin_amdgcn_rcpf(part);
            bf16x8 ap0 = { (bf16)p0, (bf16)p1, (bf16)p2,  (bf16)p3,
                           (bf16)p4, (bf16)p5, (bf16)p6,  (bf16)p7 };
            bf16x8 ap1 = { (bf16)p8, (bf16)p9, (bf16)p10, (bf16)p11,
                           (bf16)p48, (bf16)0.f, (bf16)0.f, (bf16)0.f };
            bf16x8 av00, av01, av10, av11;
            {
                const int fr0 = h * 32 + lm, fr1 = h * 32 + 16 + lm;
                av00 = *(const bf16x8*)&lds[VB + fr0 * 64 + (((0 + lq) ^ (fr0 & 7)) << 3)];
                av01 = *(const bf16x8*)&lds[VB + fr1 * 64 + (((0 + lq) ^ (fr1 & 7)) << 3)];
                av10 = *(const bf16x8*)&lds[VB + fr0 * 64 + (((4 + lq) ^ (fr0 & 7)) << 3)];
                av11 = *(const bf16x8*)&lds[VB + fr1 * 64 + (((4 + lq) ^ (fr1 & 7)) << 3)];
            }
            f32x4 o0 = MFMA16(av00, ap0, zf);
            o0 = MFMA16(av10, ap1, o0);
            f32x4 o1 = MFMA16(av01, ap0, zf);
            o1 = MFMA16(av11, ap1, o1);
            o0 *= rin;
            o1 *= rin;
            if (wid < 3 || lm == 0) {
                bf16x4 w0v = { (bf16)o0[0], (bf16)o0[1], (bf16)o0[2], (bf16)o0[3] };
                bf16x4 w1v = { (bf16)o1[0], (bf16)o1[1], (bf16)o1[2], (bf16)o1[3] };
                *(bf16x4*)&lds[QB + qrow * ST + h * 32 + lq * 4]      = w0v;
                *(bf16x4*)&lds[QB + qrow * ST + h * 32 + 16 + lq * 4] = w1v;
            }
        }
    }
    // NO __syncthreads here: proj wave tt reads exactly the O rows (tt*16+lm) that
    // THIS wave wrote above; DS ops are processed in wave order, so the read
    // observes the write. The fence only stops compiler reordering.
    asm volatile("" ::: "memory");

    // ---------------- Phase 3: proj swapped: mfma(W^T, O); float4 stores ----------------
    {
        const int tt = wid;
        bf16x8 of[3];
        #pragma unroll
        for (int ks = 0; ks < 3; ++ks)
            of[ks] = *(const bf16x8*)&lds[QB + (tt * 16 + lm) * ST + ks * 32 + lq * 8];
        const int token = tt * 16 + lm;
        const int tv = (token < 49) ? token : 0;
        const int pr = tv / 7, pc = tv - pr * 7;
        float* obase = out + ((size_t)(b * 224 + h0 + pr) * 224 + (w0 + pc)) * 96 + lq * 4;
        #pragma unroll
        for (int ft = 0; ft < 6; ++ft) {
            bf16x8 wp[3];
            #pragma unroll
            for (int ks = 0; ks < 3; ++ks)
                wp[ks] = *(const bf16x8*)&projwT[(size_t)(ft * 16 + lm) * 96 + ks * 32 + lq * 8];
            f32x4 acc = *(const f32x4*)(proj_b + ft * 16 + lq * 4);
            #pragma unroll
            for (int ks = 0; ks < 3; ++ks)
                acc = MFMA16(wp[ks], of[ks], acc);
            if (token < 49)
                *(f32x4*)(obase + ft * 16) = acc;
        }
    }
}

extern "C" void kernel_launch(void* const* d_in, const int* in_sizes, int n_in,
                              void* d_out, int out_size, void* d_ws, size_t ws_size,
                              hipStream_t stream) {
    const float* x      = (const float*)d_in[0];
    const float* qkv_w  = (const float*)d_in[1];
    const float* qkv_b  = (const float*)d_in[2];
    const float* proj_w = (const float*)d_in[3];
    const float* proj_b = (const float*)d_in[4];
    float* out = (float*)d_out;

    bf16* wT = (bf16*)d_ws;                 // 288*96 + 96*96 bf16 = 73728 B
    const int n_w = 288 * 96 + 96 * 96;
    prep_weights<<<(n_w + 255) / 256, 256, 0, stream>>>(qkv_w, proj_w, wT);
    win_attn_kernel<<<8192, 256, 0, stream>>>(x, qkv_b, proj_b,
                                              wT, wT + 288 * 96, out);
}